// Round 14
// baseline (249.835 us; speedup 1.0000x reference)
//
#include <hip/hip_runtime.h>

#define T_ 2048
#define H_ 1024
#define E_ 8
#define I_ 2048

typedef short bf16x8 __attribute__((ext_vector_type(8)));
typedef float f32x4 __attribute__((ext_vector_type(4)));
typedef unsigned short u16x8 __attribute__((ext_vector_type(8)));

__device__ __forceinline__ unsigned short f2bf(float f) {
  unsigned u = __builtin_bit_cast(unsigned, f);
  u += 0x7fffu + ((u >> 16) & 1u);   // RNE (finite inputs only)
  return (unsigned short)(u >> 16);
}

__device__ __forceinline__ float bf2f(unsigned short h) {
  unsigned u = ((unsigned)h) << 16;
  return __builtin_bit_cast(float, u);
}

#define GLOAD_LDS16(g, l)                                                     \
  __builtin_amdgcn_global_load_lds(                                           \
      (const __attribute__((address_space(1))) unsigned int*)(g),             \
      (__attribute__((address_space(3))) unsigned int*)(l), 16, 0, 0)

// ---------------- fp32 -> bf16 linear convert (hs only) --------------------
__global__ __launch_bounds__(256) void cvt_kernel(const float* __restrict__ s,
                                                  unsigned short* __restrict__ d,
                                                  int n8) {
  int i = blockIdx.x * blockDim.x + threadIdx.x;
  if (i >= n8) return;
  const float4* s4 = (const float4*)s;
  float4 a = s4[2 * i], b = s4[2 * i + 1];
  u16x8 v;
  v[0] = f2bf(a.x); v[1] = f2bf(a.y); v[2] = f2bf(a.z); v[3] = f2bf(a.w);
  v[4] = f2bf(b.x); v[5] = f2bf(b.y); v[6] = f2bf(b.z); v[7] = f2bf(b.w);
  *(u16x8*)(d + (size_t)i * 8) = v;
}

// -------- pack w13 (r12-exact): fp32 contiguous -> bf16 tiles --------------
// tiles [e][nt=32][kt=16][r=128][c=64]; r<64 gate i=nt*64+r, r>=64 up.
// chunk c (8 shorts) stored at slot c^(r&7).
__global__ __launch_bounds__(256) void pack_w13(const float* __restrict__ src,
                                                unsigned short* __restrict__ dst) {
  int g = blockIdx.x * 256 + threadIdx.x;
#pragma unroll
  for (int j = 0; j < 4; ++j) {
    size_t fo = ((size_t)g * 4 + j) * 8;
    int e = (int)(fo >> 22);
    int grow = (int)((fo >> 10) & 4095);
    int col = (int)(fo & 1023);
    int nt, r;
    if (grow < 2048) { nt = grow >> 6; r = grow & 63; }
    else             { int i2 = grow - 2048; nt = i2 >> 6; r = 64 + (i2 & 63); }
    int kt = col >> 6;
    int c = (col & 63) >> 3;
    const float4* s = (const float4*)(src + fo);
    float4 a = s[0], b = s[1];
    u16x8 o;
    o[0] = f2bf(a.x); o[1] = f2bf(a.y); o[2] = f2bf(a.z); o[3] = f2bf(a.w);
    o[4] = f2bf(b.x); o[5] = f2bf(b.y); o[6] = f2bf(b.z); o[7] = f2bf(b.w);
    size_t tb = (size_t)((e * 32 + nt) * 16 + kt);
    *(u16x8*)(dst + tb * 8192 + r * 64 + ((c ^ (r & 7)) * 8)) = o;
  }
}

// -------- pack w2 (r12-exact): fp32 contiguous -> bf16 tiles ---------------
// tiles [e][nt=8][kt=32][r=128][c=64]; r = h&127, nt = h>>7.
__global__ __launch_bounds__(256) void pack_w2(const float* __restrict__ src,
                                               unsigned short* __restrict__ dst) {
  int g = blockIdx.x * 256 + threadIdx.x;
#pragma unroll
  for (int j = 0; j < 4; ++j) {
    size_t fo = ((size_t)g * 4 + j) * 8;
    int e = (int)(fo >> 21);
    int h = (int)((fo >> 11) & 1023);
    int col = (int)(fo & 2047);
    int nt = h >> 7, r = h & 127;
    int kt = col >> 6;
    int c = (col & 63) >> 3;
    const float4* s = (const float4*)(src + fo);
    float4 a = s[0], b = s[1];
    u16x8 o;
    o[0] = f2bf(a.x); o[1] = f2bf(a.y); o[2] = f2bf(a.z); o[3] = f2bf(a.w);
    o[4] = f2bf(b.x); o[5] = f2bf(b.y); o[6] = f2bf(b.z); o[7] = f2bf(b.w);
    size_t tb = (size_t)((e * 8 + nt) * 32 + kt);
    *(u16x8*)(dst + tb * 8192 + r * 64 + ((c ^ (r & 7)) * 8)) = o;
  }
}

// ---------------- router: softmax + top2 + expert compaction ----------------
__global__ void router_kernel(const float* __restrict__ logits,
                              int* __restrict__ cnt,
                              int* __restrict__ plist,
                              float* __restrict__ wlist) {
  int t = blockIdx.x * blockDim.x + threadIdx.x;
  if (t >= T_) return;
  float l[E_];
#pragma unroll
  for (int e = 0; e < E_; ++e) l[e] = logits[t * E_ + e];
  int i0 = 0;
#pragma unroll
  for (int e = 1; e < E_; ++e) if (l[e] > l[i0]) i0 = e;
  int i1 = (i0 == 0) ? 1 : 0;
#pragma unroll
  for (int e = 0; e < E_; ++e) if (e != i0 && l[e] > l[i1]) i1 = e;
  float w1 = 1.f / (1.f + __expf(l[i0] - l[i1]));
  float w0 = 1.f - w1;
  int s0 = atomicAdd(&cnt[i0], 1);
  plist[i0 * T_ + s0] = 2 * t;
  wlist[i0 * T_ + s0] = w0;
  int s1 = atomicAdd(&cnt[i1], 1);
  plist[i1 * T_ + s1] = 2 * t + 1;
  wlist[i1 * T_ + s1] = w1;
}

// ---------------- GEMM1: act = silu(hs*w13_g)*(hs*w13_u)*w ------------------
// r12 tiles (BM=128, BN=64-pair, BK=64, 8 waves, r12 swizzle) with NEW sync:
// 4 LDS buffers, stage 2 iters ahead, ONE barrier/kt, vmcnt(8), setprio MFMA.
__global__ __launch_bounds__(512, 2) void gemm1_kernel(
    const unsigned short* __restrict__ hs_bf,
    const unsigned short* __restrict__ w13p,
    const int* __restrict__ cnt, const int* __restrict__ plist,
    const float* __restrict__ wlist, unsigned short* __restrict__ act) {
  const int bid = blockIdx.x;
  const int e = bid & 7;
  const int mt = (bid >> 3) & 15;
  const int nt = bid >> 7;             // 0..31
  const int M = cnt[e];
  if (mt * 128 >= M) return;
  const int Mrem = M - mt * 128;
  const int n0 = nt * 64;

  __shared__ __align__(16) unsigned short As[4][128 * 64];  // 16KB x4
  __shared__ __align__(16) unsigned short Bs[4][128 * 64];  // 16KB x4

  const int tid = threadIdx.x;
  const int lane = tid & 63;
  const int wid = tid >> 6;            // 0..7
  const int l15 = lane & 15;
  const int q = lane >> 4;             // 0..3
  const int wm = (wid >> 1) * 32;
  const int wn = (wid & 1) * 32;

  const unsigned short* aSrc[2];
#pragma unroll
  for (int i = 0; i < 2; ++i) {
    int row = wid * 16 + i * 8 + (lane >> 3);
    int idx = mt * 128 + ((row < Mrem) ? row : 0);
    int p = plist[e * T_ + idx] >> 1;
    aSrc[i] = hs_bf + (size_t)p * H_ + ((lane & 7) ^ (row & 7)) * 8;
  }
  const unsigned short* bTile = w13p + (size_t)((e * 32 + nt) * 16) * 8192;

#define STAGE_G1(buf, kt)                                                     \
  do {                                                                        \
    _Pragma("unroll") for (int i = 0; i < 2; ++i)                             \
        GLOAD_LDS16(aSrc[i] + (kt) * 64, &As[buf][(wid * 16 + i * 8) * 64]);  \
    _Pragma("unroll") for (int i = 0; i < 2; ++i)                             \
        GLOAD_LDS16(bTile + (size_t)(kt) * 8192 + (wid * 2 + i) * 512 +       \
                        lane * 8,                                             \
                    &Bs[buf][(wid * 2 + i) * 512]);                           \
  } while (0)

  f32x4 accg[2][2] = {};
  f32x4 accu[2][2] = {};

  STAGE_G1(0, 0);
  STAGE_G1(1, 1);

#pragma unroll 1
  for (int kt = 0; kt < 16; ++kt) {
    const int buf = kt & 3;
    if (kt + 2 < 16) {
      STAGE_G1((kt + 2) & 3, kt + 2);
      asm volatile("s_waitcnt vmcnt(8)" ::: "memory");
    } else if (kt + 1 < 16) {
      asm volatile("s_waitcnt vmcnt(4)" ::: "memory");
    } else {
      asm volatile("s_waitcnt vmcnt(0)" ::: "memory");
    }
    __builtin_amdgcn_s_barrier();
    __builtin_amdgcn_sched_barrier(0);
    __builtin_amdgcn_s_setprio(1);
#pragma unroll
    for (int ks = 0; ks < 2; ++ks) {
      const int co = ((ks * 4 + q) ^ (l15 & 7)) * 8;
      bf16x8 a0 = *(const bf16x8*)&As[buf][(wm + l15) * 64 + co];
      bf16x8 a1 = *(const bf16x8*)&As[buf][(wm + 16 + l15) * 64 + co];
      bf16x8 g0 = *(const bf16x8*)&Bs[buf][(wn + l15) * 64 + co];
      bf16x8 g1 = *(const bf16x8*)&Bs[buf][(wn + 16 + l15) * 64 + co];
      bf16x8 u0 = *(const bf16x8*)&Bs[buf][(64 + wn + l15) * 64 + co];
      bf16x8 u1 = *(const bf16x8*)&Bs[buf][(64 + wn + 16 + l15) * 64 + co];
      accg[0][0] = __builtin_amdgcn_mfma_f32_16x16x32_bf16(a0, g0, accg[0][0], 0, 0, 0);
      accg[0][1] = __builtin_amdgcn_mfma_f32_16x16x32_bf16(a0, g1, accg[0][1], 0, 0, 0);
      accg[1][0] = __builtin_amdgcn_mfma_f32_16x16x32_bf16(a1, g0, accg[1][0], 0, 0, 0);
      accg[1][1] = __builtin_amdgcn_mfma_f32_16x16x32_bf16(a1, g1, accg[1][1], 0, 0, 0);
      accu[0][0] = __builtin_amdgcn_mfma_f32_16x16x32_bf16(a0, u0, accu[0][0], 0, 0, 0);
      accu[0][1] = __builtin_amdgcn_mfma_f32_16x16x32_bf16(a0, u1, accu[0][1], 0, 0, 0);
      accu[1][0] = __builtin_amdgcn_mfma_f32_16x16x32_bf16(a1, u0, accu[1][0], 0, 0, 0);
      accu[1][1] = __builtin_amdgcn_mfma_f32_16x16x32_bf16(a1, u1, accu[1][1], 0, 0, 0);
    }
    __builtin_amdgcn_s_setprio(0);
  }

  // epilogue: C/D row = q*4+rr, col = l15
#pragma unroll
  for (int mi = 0; mi < 2; ++mi) {
#pragma unroll
    for (int rr = 0; rr < 4; ++rr) {
      int rl = wm + mi * 16 + q * 4 + rr;
      if (rl < Mrem) {
        int idx = mt * 128 + rl;
        int p = plist[e * T_ + idx];
        float w = wlist[e * T_ + idx];
        unsigned short* dst = act + (size_t)p * I_ + n0;
#pragma unroll
        for (int ni = 0; ni < 2; ++ni) {
          float g = accg[mi][ni][rr];
          float u = accu[mi][ni][rr];
          float a = (g / (1.f + __expf(-g))) * u * w;
          dst[wn + ni * 16 + l15] = f2bf(a);
        }
      }
    }
  }
}

// ---------------- GEMM2: part[kb][p][h] = act . w2p, same new sync ----------
__global__ __launch_bounds__(512, 2) void gemm2_kernel(
    const unsigned short* __restrict__ act,
    const unsigned short* __restrict__ w2p,
    const int* __restrict__ cnt, const int* __restrict__ plist,
    unsigned short* __restrict__ part) {
  const int bid = blockIdx.x;
  const int e = bid & 7;
  const int mt = (bid >> 3) & 15;
  const int nt = (bid >> 7) & 7;
  const int kb = bid >> 10;            // 0..1
  const int M = cnt[e];
  if (mt * 128 >= M) return;
  const int Mrem = M - mt * 128;
  const int n0 = nt * 128;
  const int k0 = kb * 1024;

  __shared__ __align__(16) unsigned short As[4][128 * 64];
  __shared__ __align__(16) unsigned short Bs[4][128 * 64];

  const int tid = threadIdx.x;
  const int lane = tid & 63;
  const int wid = tid >> 6;
  const int l15 = lane & 15;
  const int q = lane >> 4;
  const int wm = (wid >> 1) * 32;
  const int wn = (wid & 1) * 64;

  const unsigned short* aSrc[2];
#pragma unroll
  for (int i = 0; i < 2; ++i) {
    int row = wid * 16 + i * 8 + (lane >> 3);
    int idx = mt * 128 + ((row < Mrem) ? row : 0);
    int p = plist[e * T_ + idx];
    aSrc[i] = act + (size_t)p * I_ + k0 + ((lane & 7) ^ (row & 7)) * 8;
  }
  const unsigned short* bTile = w2p + (size_t)((e * 8 + nt) * 32 + kb * 16) * 8192;

#define STAGE_G2(buf, kt)                                                     \
  do {                                                                        \
    _Pragma("unroll") for (int i = 0; i < 2; ++i)                             \
        GLOAD_LDS16(aSrc[i] + (kt) * 64, &As[buf][(wid * 16 + i * 8) * 64]);  \
    _Pragma("unroll") for (int i = 0; i < 2; ++i)                             \
        GLOAD_LDS16(bTile + (size_t)(kt) * 8192 + (wid * 2 + i) * 512 +       \
                        lane * 8,                                             \
                    &Bs[buf][(wid * 2 + i) * 512]);                           \
  } while (0)

  f32x4 acc[2][4] = {};

  STAGE_G2(0, 0);
  STAGE_G2(1, 1);

#pragma unroll 1
  for (int kt = 0; kt < 16; ++kt) {
    const int buf = kt & 3;
    if (kt + 2 < 16) {
      STAGE_G2((kt + 2) & 3, kt + 2);
      asm volatile("s_waitcnt vmcnt(8)" ::: "memory");
    } else if (kt + 1 < 16) {
      asm volatile("s_waitcnt vmcnt(4)" ::: "memory");
    } else {
      asm volatile("s_waitcnt vmcnt(0)" ::: "memory");
    }
    __builtin_amdgcn_s_barrier();
    __builtin_amdgcn_sched_barrier(0);
    __builtin_amdgcn_s_setprio(1);
#pragma unroll
    for (int ks = 0; ks < 2; ++ks) {
      const int co = ((ks * 4 + q) ^ (l15 & 7)) * 8;
      bf16x8 a0 = *(const bf16x8*)&As[buf][(wm + l15) * 64 + co];
      bf16x8 a1 = *(const bf16x8*)&As[buf][(wm + 16 + l15) * 64 + co];
      bf16x8 b0 = *(const bf16x8*)&Bs[buf][(wn + l15) * 64 + co];
      bf16x8 b1 = *(const bf16x8*)&Bs[buf][(wn + 16 + l15) * 64 + co];
      bf16x8 b2 = *(const bf16x8*)&Bs[buf][(wn + 32 + l15) * 64 + co];
      bf16x8 b3 = *(const bf16x8*)&Bs[buf][(wn + 48 + l15) * 64 + co];
      acc[0][0] = __builtin_amdgcn_mfma_f32_16x16x32_bf16(a0, b0, acc[0][0], 0, 0, 0);
      acc[0][1] = __builtin_amdgcn_mfma_f32_16x16x32_bf16(a0, b1, acc[0][1], 0, 0, 0);
      acc[0][2] = __builtin_amdgcn_mfma_f32_16x16x32_bf16(a0, b2, acc[0][2], 0, 0, 0);
      acc[0][3] = __builtin_amdgcn_mfma_f32_16x16x32_bf16(a0, b3, acc[0][3], 0, 0, 0);
      acc[1][0] = __builtin_amdgcn_mfma_f32_16x16x32_bf16(a1, b0, acc[1][0], 0, 0, 0);
      acc[1][1] = __builtin_amdgcn_mfma_f32_16x16x32_bf16(a1, b1, acc[1][1], 0, 0, 0);
      acc[1][2] = __builtin_amdgcn_mfma_f32_16x16x32_bf16(a1, b2, acc[1][2], 0, 0, 0);
      acc[1][3] = __builtin_amdgcn_mfma_f32_16x16x32_bf16(a1, b3, acc[1][3], 0, 0, 0);
    }
    __builtin_amdgcn_s_setprio(0);
  }

#pragma unroll
  for (int mi = 0; mi < 2; ++mi) {
#pragma unroll
    for (int rr = 0; rr < 4; ++rr) {
      int rl = wm + mi * 16 + q * 4 + rr;
      if (rl < Mrem) {
        int p = plist[e * T_ + mt * 128 + rl];
        unsigned short* dst = part + ((size_t)kb * 2 * T_ + p) * H_ + n0 + wn + l15;
#pragma unroll
        for (int ni = 0; ni < 4; ++ni)
          dst[ni * 16] = f2bf(acc[mi][ni][rr]);
      }
    }
  }
}

// ---------- reduce: out[t,h] = sum_{kb,pp} bf16 part[kb][2t+pp][h] ----------
__global__ __launch_bounds__(256) void reduce_kernel(const unsigned short* __restrict__ part,
                                                     float* __restrict__ out) {
  int i = blockIdx.x * blockDim.x + threadIdx.x;   // over T_*H_/8
  int t = i >> 7;                                  // H_/8 = 128
  int c = (i & 127) << 3;
  float s[8] = {0.f, 0.f, 0.f, 0.f, 0.f, 0.f, 0.f, 0.f};
#pragma unroll
  for (int kb = 0; kb < 2; ++kb) {
#pragma unroll
    for (int pp = 0; pp < 2; ++pp) {
      u16x8 v = *(const u16x8*)(part + ((size_t)kb * 2 * T_ + 2 * t + pp) * H_ + c);
#pragma unroll
      for (int j = 0; j < 8; ++j) s[j] += bf2f(v[j]);
    }
  }
  float* o = out + (size_t)t * H_ + c;
  *(f32x4*)o = *(f32x4*)&s[0];
  *(f32x4*)(o + 4) = *(f32x4*)&s[4];
}

extern "C" void kernel_launch(void* const* d_in, const int* in_sizes, int n_in,
                              void* d_out, int out_size, void* d_ws, size_t ws_size,
                              hipStream_t stream) {
  const float* hs     = (const float*)d_in[0];
  const float* logits = (const float*)d_in[1];
  const float* w13    = (const float*)d_in[2];
  const float* w2     = (const float*)d_in[3];
  float* out = (float*)d_out;

  char* ws = (char*)d_ws;
  size_t off = 0;
  int* cnt = (int*)(ws + off);           off += 256;
  int* plist = (int*)(ws + off);         off += (size_t)E_ * T_ * 4;
  float* wlist = (float*)(ws + off);     off += (size_t)E_ * T_ * 4;
  unsigned short* act = (unsigned short*)(ws + off);   off += (size_t)2 * T_ * I_ * 2;
  unsigned short* hs_bf = (unsigned short*)(ws + off); off += (size_t)T_ * H_ * 2;
  unsigned short* part = (unsigned short*)(ws + off);  off += (size_t)2 * 2 * T_ * H_ * 2;
  unsigned short* w13p = (unsigned short*)(ws + off);  off += (size_t)E_ * 2 * I_ * H_ * 2;
  unsigned short* w2p = (unsigned short*)(ws + off);   off += (size_t)E_ * H_ * I_ * 2;
  // total ~137 MB

  hipMemsetAsync(cnt, 0, 256, stream);

  const int nHs = T_ * H_ / 8;
  cvt_kernel<<<(nHs + 255) / 256, 256, 0, stream>>>(hs, hs_bf, nHs);
  router_kernel<<<T_ / 256, 256, 0, stream>>>(logits, cnt, plist, wlist);
  pack_w13<<<4096, 256, 0, stream>>>(w13, w13p);
  pack_w2<<<2048, 256, 0, stream>>>(w2, w2p);

  gemm1_kernel<<<32 * 16 * 8, 512, 0, stream>>>(hs_bf, w13p, cnt, plist, wlist, act);
  gemm2_kernel<<<2 * 8 * 16 * 8, 512, 0, stream>>>(act, w2p, cnt, plist, part);
  reduce_kernel<<<T_ * H_ / 8 / 256, 256, 0, stream>>>(part, out);
}

// Round 15
// 206.315 us; speedup vs baseline: 1.2109x; 1.2109x over previous
//
#include <hip/hip_runtime.h>

#define T_ 2048
#define H_ 1024
#define E_ 8
#define I_ 2048

typedef short bf16x8 __attribute__((ext_vector_type(8)));
typedef float f32x4 __attribute__((ext_vector_type(4)));
typedef unsigned short u16x8 __attribute__((ext_vector_type(8)));

__device__ __forceinline__ unsigned short f2bf(float f) {
  unsigned u = __builtin_bit_cast(unsigned, f);
  u += 0x7fffu + ((u >> 16) & 1u);   // RNE (finite inputs only)
  return (unsigned short)(u >> 16);
}

__device__ __forceinline__ float bf2f(unsigned short h) {
  unsigned u = ((unsigned)h) << 16;
  return __builtin_bit_cast(float, u);
}

#define GLOAD_LDS16(g, l)                                                     \
  __builtin_amdgcn_global_load_lds(                                           \
      (const __attribute__((address_space(1))) unsigned int*)(g),             \
      (__attribute__((address_space(3))) unsigned int*)(l), 16, 0, 0)

// ---------------- fp32 -> bf16 linear convert (hs only) --------------------
__global__ __launch_bounds__(256) void cvt_kernel(const float* __restrict__ s,
                                                  unsigned short* __restrict__ d,
                                                  int n8) {
  int i = blockIdx.x * blockDim.x + threadIdx.x;
  if (i >= n8) return;
  const float4* s4 = (const float4*)s;
  float4 a = s4[2 * i], b = s4[2 * i + 1];
  u16x8 v;
  v[0] = f2bf(a.x); v[1] = f2bf(a.y); v[2] = f2bf(a.z); v[3] = f2bf(a.w);
  v[4] = f2bf(b.x); v[5] = f2bf(b.y); v[6] = f2bf(b.z); v[7] = f2bf(b.w);
  *(u16x8*)(d + (size_t)i * 8) = v;
}

// -------- pack w13 (r12-exact): fp32 contiguous -> bf16 tiles --------------
// tiles [e][nt=32][kt=16][r=128][c=64]; r<64 gate i=nt*64+r, r>=64 up.
// chunk c (8 shorts) stored at slot c^(r&7).
__global__ __launch_bounds__(256) void pack_w13(const float* __restrict__ src,
                                                unsigned short* __restrict__ dst) {
  int g = blockIdx.x * 256 + threadIdx.x;
#pragma unroll
  for (int j = 0; j < 4; ++j) {
    size_t fo = ((size_t)g * 4 + j) * 8;
    int e = (int)(fo >> 22);
    int grow = (int)((fo >> 10) & 4095);
    int col = (int)(fo & 1023);
    int nt, r;
    if (grow < 2048) { nt = grow >> 6; r = grow & 63; }
    else             { int i2 = grow - 2048; nt = i2 >> 6; r = 64 + (i2 & 63); }
    int kt = col >> 6;
    int c = (col & 63) >> 3;
    const float4* s = (const float4*)(src + fo);
    float4 a = s[0], b = s[1];
    u16x8 o;
    o[0] = f2bf(a.x); o[1] = f2bf(a.y); o[2] = f2bf(a.z); o[3] = f2bf(a.w);
    o[4] = f2bf(b.x); o[5] = f2bf(b.y); o[6] = f2bf(b.z); o[7] = f2bf(b.w);
    size_t tb = (size_t)((e * 32 + nt) * 16 + kt);
    *(u16x8*)(dst + tb * 8192 + r * 64 + ((c ^ (r & 7)) * 8)) = o;
  }
}

// -------- pack w2 (r12-exact): fp32 contiguous -> bf16 tiles ---------------
// tiles [e][nt=8][kt=32][r=128][c=64]; r = h&127, nt = h>>7.
__global__ __launch_bounds__(256) void pack_w2(const float* __restrict__ src,
                                               unsigned short* __restrict__ dst) {
  int g = blockIdx.x * 256 + threadIdx.x;
#pragma unroll
  for (int j = 0; j < 4; ++j) {
    size_t fo = ((size_t)g * 4 + j) * 8;
    int e = (int)(fo >> 21);
    int h = (int)((fo >> 11) & 1023);
    int col = (int)(fo & 2047);
    int nt = h >> 7, r = h & 127;
    int kt = col >> 6;
    int c = (col & 63) >> 3;
    const float4* s = (const float4*)(src + fo);
    float4 a = s[0], b = s[1];
    u16x8 o;
    o[0] = f2bf(a.x); o[1] = f2bf(a.y); o[2] = f2bf(a.z); o[3] = f2bf(a.w);
    o[4] = f2bf(b.x); o[5] = f2bf(b.y); o[6] = f2bf(b.z); o[7] = f2bf(b.w);
    size_t tb = (size_t)((e * 8 + nt) * 32 + kt);
    *(u16x8*)(dst + tb * 8192 + r * 64 + ((c ^ (r & 7)) * 8)) = o;
  }
}

// ---------------- router: softmax + top2 + expert compaction ----------------
__global__ void router_kernel(const float* __restrict__ logits,
                              int* __restrict__ cnt,
                              int* __restrict__ plist,
                              float* __restrict__ wlist) {
  int t = blockIdx.x * blockDim.x + threadIdx.x;
  if (t >= T_) return;
  float l[E_];
#pragma unroll
  for (int e = 0; e < E_; ++e) l[e] = logits[t * E_ + e];
  int i0 = 0;
#pragma unroll
  for (int e = 1; e < E_; ++e) if (l[e] > l[i0]) i0 = e;
  int i1 = (i0 == 0) ? 1 : 0;
#pragma unroll
  for (int e = 0; e < E_; ++e) if (e != i0 && l[e] > l[i1]) i1 = e;
  float w1 = 1.f / (1.f + __expf(l[i0] - l[i1]));
  float w0 = 1.f - w1;
  int s0 = atomicAdd(&cnt[i0], 1);
  plist[i0 * T_ + s0] = 2 * t;
  wlist[i0 * T_ + s0] = w0;
  int s1 = atomicAdd(&cnt[i1], 1);
  plist[i1 * T_ + s1] = 2 * t + 1;
  wlist[i1 * T_ + s1] = w1;
}

// ---------------- GEMM1: act = silu(hs*w13_g)*(hs*w13_u)*w ------------------
// r12 schedule, halved block: BM=64, BN=64-pair, BK=64, 4 waves, 48KB LDS
// -> 3 blk/CU. Stage 6 gloads/wave, counted vmcnt(6), 2 barriers/kt.
__global__ __launch_bounds__(256, 3) void gemm1_kernel(
    const unsigned short* __restrict__ hs_bf,
    const unsigned short* __restrict__ w13p,
    const int* __restrict__ cnt, const int* __restrict__ plist,
    const float* __restrict__ wlist, unsigned short* __restrict__ act) {
  const int bid = blockIdx.x;
  const int e = bid & 7;
  const int mt = (bid >> 3) & 15;      // 64-row tiles
  const int nt = bid >> 7;             // 0..31
  const int M = cnt[e];
  if (mt * 64 >= M) return;
  const int Mrem = M - mt * 64;
  const int n0 = nt * 64;

  __shared__ __align__(16) unsigned short As[2][64 * 64];   // 8KB x2
  __shared__ __align__(16) unsigned short Bs[2][128 * 64];  // 16KB x2

  const int tid = threadIdx.x;
  const int lane = tid & 63;
  const int wid = tid >> 6;            // 0..3
  const int l15 = lane & 15;
  const int q = lane >> 4;             // 0..3
  const int wm = (wid >> 1) * 32;
  const int wn = (wid & 1) * 32;

  const unsigned short* aSrc[2];
#pragma unroll
  for (int i = 0; i < 2; ++i) {
    int row = wid * 16 + i * 8 + (lane >> 3);
    int idx = mt * 64 + ((row < Mrem) ? row : 0);
    int p = plist[e * T_ + idx] >> 1;
    aSrc[i] = hs_bf + (size_t)p * H_ + ((lane & 7) ^ (row & 7)) * 8;
  }
  const unsigned short* bTile = w13p + (size_t)((e * 32 + nt) * 16) * 8192;

#define STAGE_G1(buf, kt)                                                     \
  do {                                                                        \
    _Pragma("unroll") for (int i = 0; i < 2; ++i)                             \
        GLOAD_LDS16(aSrc[i] + (kt) * 64, &As[buf][(wid * 16 + i * 8) * 64]);  \
    _Pragma("unroll") for (int i = 0; i < 4; ++i)                             \
        GLOAD_LDS16(bTile + (size_t)(kt) * 8192 + (wid * 4 + i) * 512 +       \
                        lane * 8,                                             \
                    &Bs[buf][(wid * 4 + i) * 512]);                           \
  } while (0)

  f32x4 accg[2][2] = {};
  f32x4 accu[2][2] = {};

  STAGE_G1(0, 0);
#pragma unroll 1
  for (int kt = 0; kt < 16; ++kt) {
    const int buf = kt & 1;
    if (kt + 1 < 16) {
      STAGE_G1(buf ^ 1, kt + 1);
      asm volatile("s_waitcnt vmcnt(6)" ::: "memory");
    } else {
      asm volatile("s_waitcnt vmcnt(0)" ::: "memory");
    }
    __builtin_amdgcn_s_barrier();
    __builtin_amdgcn_sched_barrier(0);
#pragma unroll
    for (int ks = 0; ks < 2; ++ks) {
      const int co = ((ks * 4 + q) ^ (l15 & 7)) * 8;
      bf16x8 a0 = *(const bf16x8*)&As[buf][(wm + l15) * 64 + co];
      bf16x8 a1 = *(const bf16x8*)&As[buf][(wm + 16 + l15) * 64 + co];
      bf16x8 g0 = *(const bf16x8*)&Bs[buf][(wn + l15) * 64 + co];
      bf16x8 g1 = *(const bf16x8*)&Bs[buf][(wn + 16 + l15) * 64 + co];
      bf16x8 u0 = *(const bf16x8*)&Bs[buf][(64 + wn + l15) * 64 + co];
      bf16x8 u1 = *(const bf16x8*)&Bs[buf][(64 + wn + 16 + l15) * 64 + co];
      accg[0][0] = __builtin_amdgcn_mfma_f32_16x16x32_bf16(a0, g0, accg[0][0], 0, 0, 0);
      accg[0][1] = __builtin_amdgcn_mfma_f32_16x16x32_bf16(a0, g1, accg[0][1], 0, 0, 0);
      accg[1][0] = __builtin_amdgcn_mfma_f32_16x16x32_bf16(a1, g0, accg[1][0], 0, 0, 0);
      accg[1][1] = __builtin_amdgcn_mfma_f32_16x16x32_bf16(a1, g1, accg[1][1], 0, 0, 0);
      accu[0][0] = __builtin_amdgcn_mfma_f32_16x16x32_bf16(a0, u0, accu[0][0], 0, 0, 0);
      accu[0][1] = __builtin_amdgcn_mfma_f32_16x16x32_bf16(a0, u1, accu[0][1], 0, 0, 0);
      accu[1][0] = __builtin_amdgcn_mfma_f32_16x16x32_bf16(a1, u0, accu[1][0], 0, 0, 0);
      accu[1][1] = __builtin_amdgcn_mfma_f32_16x16x32_bf16(a1, u1, accu[1][1], 0, 0, 0);
    }
    __builtin_amdgcn_sched_barrier(0);
    __builtin_amdgcn_s_barrier();
  }

  // epilogue: C/D row = q*4+rr, col = l15
#pragma unroll
  for (int mi = 0; mi < 2; ++mi) {
#pragma unroll
    for (int rr = 0; rr < 4; ++rr) {
      int rl = wm + mi * 16 + q * 4 + rr;
      if (rl < Mrem) {
        int idx = mt * 64 + rl;
        int p = plist[e * T_ + idx];
        float w = wlist[e * T_ + idx];
        unsigned short* dst = act + (size_t)p * I_ + n0;
#pragma unroll
        for (int ni = 0; ni < 2; ++ni) {
          float g = accg[mi][ni][rr];
          float u = accu[mi][ni][rr];
          float a = (g / (1.f + __expf(-g))) * u * w;
          dst[wn + ni * 16 + l15] = f2bf(a);
        }
      }
    }
  }
}

// ---------------- GEMM2: part[kb][p][h] = act . w2p -------------------------
// Same halved structure: BM=64, BN=128, BK=64, 4 waves, 48KB, vmcnt(6).
__global__ __launch_bounds__(256, 3) void gemm2_kernel(
    const unsigned short* __restrict__ act,
    const unsigned short* __restrict__ w2p,
    const int* __restrict__ cnt, const int* __restrict__ plist,
    unsigned short* __restrict__ part) {
  const int bid = blockIdx.x;
  const int e = bid & 7;
  const int mt = (bid >> 3) & 15;      // 64-row tiles
  const int nt = (bid >> 7) & 7;
  const int kb = bid >> 10;            // 0..1
  const int M = cnt[e];
  if (mt * 64 >= M) return;
  const int Mrem = M - mt * 64;
  const int n0 = nt * 128;
  const int k0 = kb * 1024;

  __shared__ __align__(16) unsigned short As[2][64 * 64];
  __shared__ __align__(16) unsigned short Bs[2][128 * 64];

  const int tid = threadIdx.x;
  const int lane = tid & 63;
  const int wid = tid >> 6;            // 0..3
  const int l15 = lane & 15;
  const int q = lane >> 4;
  const int wm = (wid >> 1) * 32;
  const int wn = (wid & 1) * 64;

  const unsigned short* aSrc[2];
#pragma unroll
  for (int i = 0; i < 2; ++i) {
    int row = wid * 16 + i * 8 + (lane >> 3);
    int idx = mt * 64 + ((row < Mrem) ? row : 0);
    int p = plist[e * T_ + idx];
    aSrc[i] = act + (size_t)p * I_ + k0 + ((lane & 7) ^ (row & 7)) * 8;
  }
  const unsigned short* bTile = w2p + (size_t)((e * 8 + nt) * 32 + kb * 16) * 8192;

#define STAGE_G2(buf, kt)                                                     \
  do {                                                                        \
    _Pragma("unroll") for (int i = 0; i < 2; ++i)                             \
        GLOAD_LDS16(aSrc[i] + (kt) * 64, &As[buf][(wid * 16 + i * 8) * 64]);  \
    _Pragma("unroll") for (int i = 0; i < 4; ++i)                             \
        GLOAD_LDS16(bTile + (size_t)(kt) * 8192 + (wid * 4 + i) * 512 +       \
                        lane * 8,                                             \
                    &Bs[buf][(wid * 4 + i) * 512]);                           \
  } while (0)

  f32x4 acc[2][4] = {};

  STAGE_G2(0, 0);
#pragma unroll 1
  for (int kt = 0; kt < 16; ++kt) {
    const int buf = kt & 1;
    if (kt + 1 < 16) {
      STAGE_G2(buf ^ 1, kt + 1);
      asm volatile("s_waitcnt vmcnt(6)" ::: "memory");
    } else {
      asm volatile("s_waitcnt vmcnt(0)" ::: "memory");
    }
    __builtin_amdgcn_s_barrier();
    __builtin_amdgcn_sched_barrier(0);
#pragma unroll
    for (int ks = 0; ks < 2; ++ks) {
      const int co = ((ks * 4 + q) ^ (l15 & 7)) * 8;
      bf16x8 a0 = *(const bf16x8*)&As[buf][(wm + l15) * 64 + co];
      bf16x8 a1 = *(const bf16x8*)&As[buf][(wm + 16 + l15) * 64 + co];
      bf16x8 b0 = *(const bf16x8*)&Bs[buf][(wn + l15) * 64 + co];
      bf16x8 b1 = *(const bf16x8*)&Bs[buf][(wn + 16 + l15) * 64 + co];
      bf16x8 b2 = *(const bf16x8*)&Bs[buf][(wn + 32 + l15) * 64 + co];
      bf16x8 b3 = *(const bf16x8*)&Bs[buf][(wn + 48 + l15) * 64 + co];
      acc[0][0] = __builtin_amdgcn_mfma_f32_16x16x32_bf16(a0, b0, acc[0][0], 0, 0, 0);
      acc[0][1] = __builtin_amdgcn_mfma_f32_16x16x32_bf16(a0, b1, acc[0][1], 0, 0, 0);
      acc[0][2] = __builtin_amdgcn_mfma_f32_16x16x32_bf16(a0, b2, acc[0][2], 0, 0, 0);
      acc[0][3] = __builtin_amdgcn_mfma_f32_16x16x32_bf16(a0, b3, acc[0][3], 0, 0, 0);
      acc[1][0] = __builtin_amdgcn_mfma_f32_16x16x32_bf16(a1, b0, acc[1][0], 0, 0, 0);
      acc[1][1] = __builtin_amdgcn_mfma_f32_16x16x32_bf16(a1, b1, acc[1][1], 0, 0, 0);
      acc[1][2] = __builtin_amdgcn_mfma_f32_16x16x32_bf16(a1, b2, acc[1][2], 0, 0, 0);
      acc[1][3] = __builtin_amdgcn_mfma_f32_16x16x32_bf16(a1, b3, acc[1][3], 0, 0, 0);
    }
    __builtin_amdgcn_sched_barrier(0);
    __builtin_amdgcn_s_barrier();
  }

#pragma unroll
  for (int mi = 0; mi < 2; ++mi) {
#pragma unroll
    for (int rr = 0; rr < 4; ++rr) {
      int rl = wm + mi * 16 + q * 4 + rr;
      if (rl < Mrem) {
        int p = plist[e * T_ + mt * 64 + rl];
        unsigned short* dst = part + ((size_t)kb * 2 * T_ + p) * H_ + n0 + wn + l15;
#pragma unroll
        for (int ni = 0; ni < 4; ++ni)
          dst[ni * 16] = f2bf(acc[mi][ni][rr]);
      }
    }
  }
}

// ---------- reduce: out[t,h] = sum_{kb,pp} bf16 part[kb][2t+pp][h] ----------
__global__ __launch_bounds__(256) void reduce_kernel(const unsigned short* __restrict__ part,
                                                     float* __restrict__ out) {
  int i = blockIdx.x * blockDim.x + threadIdx.x;   // over T_*H_/8
  int t = i >> 7;                                  // H_/8 = 128
  int c = (i & 127) << 3;
  float s[8] = {0.f, 0.f, 0.f, 0.f, 0.f, 0.f, 0.f, 0.f};
#pragma unroll
  for (int kb = 0; kb < 2; ++kb) {
#pragma unroll
    for (int pp = 0; pp < 2; ++pp) {
      u16x8 v = *(const u16x8*)(part + ((size_t)kb * 2 * T_ + 2 * t + pp) * H_ + c);
#pragma unroll
      for (int j = 0; j < 8; ++j) s[j] += bf2f(v[j]);
    }
  }
  float* o = out + (size_t)t * H_ + c;
  *(f32x4*)o = *(f32x4*)&s[0];
  *(f32x4*)(o + 4) = *(f32x4*)&s[4];
}

extern "C" void kernel_launch(void* const* d_in, const int* in_sizes, int n_in,
                              void* d_out, int out_size, void* d_ws, size_t ws_size,
                              hipStream_t stream) {
  const float* hs     = (const float*)d_in[0];
  const float* logits = (const float*)d_in[1];
  const float* w13    = (const float*)d_in[2];
  const float* w2     = (const float*)d_in[3];
  float* out = (float*)d_out;

  char* ws = (char*)d_ws;
  size_t off = 0;
  int* cnt = (int*)(ws + off);           off += 256;
  int* plist = (int*)(ws + off);         off += (size_t)E_ * T_ * 4;
  float* wlist = (float*)(ws + off);     off += (size_t)E_ * T_ * 4;
  unsigned short* act = (unsigned short*)(ws + off);   off += (size_t)2 * T_ * I_ * 2;
  unsigned short* hs_bf = (unsigned short*)(ws + off); off += (size_t)T_ * H_ * 2;
  unsigned short* part = (unsigned short*)(ws + off);  off += (size_t)2 * 2 * T_ * H_ * 2;
  unsigned short* w13p = (unsigned short*)(ws + off);  off += (size_t)E_ * 2 * I_ * H_ * 2;
  unsigned short* w2p = (unsigned short*)(ws + off);   off += (size_t)E_ * H_ * I_ * 2;
  // total ~137 MB

  hipMemsetAsync(cnt, 0, 256, stream);

  const int nHs = T_ * H_ / 8;
  cvt_kernel<<<(nHs + 255) / 256, 256, 0, stream>>>(hs, hs_bf, nHs);
  router_kernel<<<T_ / 256, 256, 0, stream>>>(logits, cnt, plist, wlist);
  pack_w13<<<4096, 256, 0, stream>>>(w13, w13p);
  pack_w2<<<2048, 256, 0, stream>>>(w2, w2p);

  gemm1_kernel<<<8 * 16 * 32, 256, 0, stream>>>(hs_bf, w13p, cnt, plist, wlist, act);
  gemm2_kernel<<<8 * 16 * 8 * 2, 256, 0, stream>>>(act, w2p, cnt, plist, part);
  reduce_kernel<<<T_ * H_ / 8 / 256, 256, 0, stream>>>(part, out);
}